// Round 1
// baseline (326.370 us; speedup 1.0000x reference)
//
#include <hip/hip_runtime.h>
#include <hip/hip_bf16.h>

typedef __bf16 bf16_t;
typedef _Float16 f16_t;
typedef bf16_t bf16x8 __attribute__((ext_vector_type(8)));
typedef f16_t  f16x8  __attribute__((ext_vector_type(8)));
typedef float  floatx4 __attribute__((ext_vector_type(4)));

#define DEV static __device__ __forceinline__

DEV floatx4 mfma_bf16(bf16x8 a, bf16x8 b, floatx4 c) {
  return __builtin_amdgcn_mfma_f32_16x16x32_bf16(a, b, c, 0, 0, 0);
}
DEV floatx4 mfma_f16(f16x8 a, f16x8 b, floatx4 c) {
  return __builtin_amdgcn_mfma_f32_16x16x32_f16(a, b, c, 0, 0, 0);
}
// async global->LDS, 16B per lane; lds dst = wave-uniform base + lane*16
DEV void async_ld16(void* lds, const void* g) {
  __builtin_amdgcn_global_load_lds(
      (const __attribute__((address_space(1))) unsigned int*)g,
      (__attribute__((address_space(3))) unsigned int*)lds, 16, 0, 0);
}

// ---------------------------------------------------------------------------
// Kernel 1: K = relu(X@Wk1+bk1)@Wk2+bk2 in split-bf16 (hi/lo), 64 rows/block.
// K stored as separate hi/lo bf16 arrays, row-major (nh*1024+l, 128).
// ---------------------------------------------------------------------------
__global__ __launch_bounds__(256, 2) void mlp_k_kernel(
    const float* __restrict__ X, const float* __restrict__ W1,
    const float* __restrict__ b1, const float* __restrict__ W2,
    const float* __restrict__ b2, bf16_t* __restrict__ Khi,
    bf16_t* __restrict__ Klo) {
  __shared__ __align__(16) bf16_t sXhi[64 * 72];   // X/H/K tile, k-half, padded
  __shared__ __align__(16) bf16_t sXlo[64 * 72];
  __shared__ __align__(16) bf16_t sWhi[128 * 72];  // W transposed (n,k-half)
  __shared__ __align__(16) bf16_t sWlo[128 * 72];
  __shared__ float sB[128];

  const int tid  = threadIdx.x;
  const int lane = tid & 63;
  const int wave = tid >> 6;
  const int q    = lane >> 4;
  const int c15  = lane & 15;
  const size_t rowBase = (size_t)blockIdx.x * 64;
  const floatx4 FZ = {0.f, 0.f, 0.f, 0.f};

  floatx4 acc1[8];
  for (int i = 0; i < 8; ++i) acc1[i] = FZ;

  // ---------------- stage 1: H = relu(X@W1+b1), k-halved ----------------
  for (int kh = 0; kh < 2; ++kh) {
    __syncthreads();
    // stage X half: 64 rows x 64 cols, hi/lo
    for (int u = 0; u < 4; ++u) {
      int idx = tid + u * 256;           // 1024 float4 units
      int r = idx >> 4;
      int c4 = (idx & 15) << 2;
      float4 v = *(const float4*)(X + rowBase * 128 + (size_t)r * 128 + kh * 64 + c4);
      int o = r * 72 + c4;
      bf16_t h0 = (bf16_t)v.x, h1 = (bf16_t)v.y, h2 = (bf16_t)v.z, h3 = (bf16_t)v.w;
      sXhi[o + 0] = h0; sXhi[o + 1] = h1; sXhi[o + 2] = h2; sXhi[o + 3] = h3;
      sXlo[o + 0] = (bf16_t)(v.x - (float)h0);
      sXlo[o + 1] = (bf16_t)(v.y - (float)h1);
      sXlo[o + 2] = (bf16_t)(v.z - (float)h2);
      sXlo[o + 3] = (bf16_t)(v.w - (float)h3);
    }
    // stage W1 half, transposed: sW[n][k_local]
    for (int u = 0; u < 8; ++u) {
      int idx = tid + u * 256;           // 2048 float4 units: 64 k x 32 n4
      int k = idx >> 5;
      int n4 = (idx & 31) << 2;
      float4 v = *(const float4*)(W1 + (size_t)(kh * 64 + k) * 128 + n4);
      float vv[4] = {v.x, v.y, v.z, v.w};
      for (int i = 0; i < 4; ++i) {
        bf16_t hi = (bf16_t)vv[i];
        sWhi[(n4 + i) * 72 + k] = hi;
        sWlo[(n4 + i) * 72 + k] = (bf16_t)(vv[i] - (float)hi);
      }
    }
    if (kh == 0 && tid < 128) sB[tid] = b1[tid];
    __syncthreads();

    bf16x8 ah[2], al[2];
    for (int kc = 0; kc < 2; ++kc) {
      int ao = (wave * 16 + c15) * 72 + kc * 32 + q * 8;
      ah[kc] = *(const bf16x8*)(sXhi + ao);
      al[kc] = *(const bf16x8*)(sXlo + ao);
    }
    for (int nt = 0; nt < 8; ++nt)
      for (int kc = 0; kc < 2; ++kc) {
        int bo = (nt * 16 + c15) * 72 + kc * 32 + q * 8;
        bf16x8 bh = *(const bf16x8*)(sWhi + bo);
        bf16x8 bl = *(const bf16x8*)(sWlo + bo);
        acc1[nt] = mfma_bf16(ah[kc], bh, acc1[nt]);
        acc1[nt] = mfma_bf16(ah[kc], bl, acc1[nt]);
        acc1[nt] = mfma_bf16(al[kc], bh, acc1[nt]);
      }
  }
  float hreg[8][4];
  for (int nt = 0; nt < 8; ++nt)
    for (int r = 0; r < 4; ++r)
      hreg[nt][r] = fmaxf(acc1[nt][r] + sB[nt * 16 + c15], 0.f);

  // ---------------- stage 2: K = H@W2+b2, k-halved ----------------
  floatx4 acc2[8];
  for (int i = 0; i < 8; ++i) acc2[i] = FZ;
  for (int kh = 0; kh < 2; ++kh) {
    __syncthreads();
    // write H half hi/lo into sX (own rows only)
    for (int nt = 4 * kh; nt < 4 * kh + 4; ++nt)
      for (int r = 0; r < 4; ++r) {
        int row = wave * 16 + q * 4 + r;
        float h = hreg[nt][r];
        bf16_t hh = (bf16_t)h;
        int o = row * 72 + (nt - 4 * kh) * 16 + c15;
        sXhi[o] = hh;
        sXlo[o] = (bf16_t)(h - (float)hh);
      }
    for (int u = 0; u < 8; ++u) {
      int idx = tid + u * 256;
      int k = idx >> 5;
      int n4 = (idx & 31) << 2;
      float4 v = *(const float4*)(W2 + (size_t)(kh * 64 + k) * 128 + n4);
      float vv[4] = {v.x, v.y, v.z, v.w};
      for (int i = 0; i < 4; ++i) {
        bf16_t hi = (bf16_t)vv[i];
        sWhi[(n4 + i) * 72 + k] = hi;
        sWlo[(n4 + i) * 72 + k] = (bf16_t)(vv[i] - (float)hi);
      }
    }
    if (kh == 0 && tid < 128) sB[tid] = b2[tid];
    __syncthreads();

    bf16x8 ah[2], al[2];
    for (int kc = 0; kc < 2; ++kc) {
      int ao = (wave * 16 + c15) * 72 + kc * 32 + q * 8;
      ah[kc] = *(const bf16x8*)(sXhi + ao);
      al[kc] = *(const bf16x8*)(sXlo + ao);
    }
    for (int nt = 0; nt < 8; ++nt)
      for (int kc = 0; kc < 2; ++kc) {
        int bo = (nt * 16 + c15) * 72 + kc * 32 + q * 8;
        bf16x8 bh = *(const bf16x8*)(sWhi + bo);
        bf16x8 bl = *(const bf16x8*)(sWlo + bo);
        acc2[nt] = mfma_bf16(ah[kc], bh, acc2[nt]);
        acc2[nt] = mfma_bf16(ah[kc], bl, acc2[nt]);
        acc2[nt] = mfma_bf16(al[kc], bh, acc2[nt]);
      }
  }
  // epilogue: split K into hi/lo, LDS round-trip per column-half for coalesced stores
  for (int ch = 0; ch < 2; ++ch) {
    __syncthreads();
    for (int nt = 4 * ch; nt < 4 * ch + 4; ++nt)
      for (int r = 0; r < 4; ++r) {
        int row = wave * 16 + q * 4 + r;
        float kv = acc2[nt][r] + sB[nt * 16 + c15];
        bf16_t kh_ = (bf16_t)kv;
        int o = row * 72 + (nt - 4 * ch) * 16 + c15;
        sXhi[o] = kh_;
        sXlo[o] = (bf16_t)(kv - (float)kh_);
      }
    __syncthreads();
    for (int u = 0; u < 2; ++u) {
      int idx = tid + u * 256;           // 512 b128 units
      int r = idx >> 3;
      int c8 = (idx & 7) << 3;
      *(int4*)(Khi + rowBase * 128 + (size_t)r * 128 + ch * 64 + c8) =
          *(const int4*)(sXhi + r * 72 + c8);
      *(int4*)(Klo + rowBase * 128 + (size_t)r * 128 + ch * 64 + c8) =
          *(const int4*)(sXlo + r * 72 + c8);
    }
  }
}

// ---------------------------------------------------------------------------
// Kernel 2: V-MLP in fp16; stage 2 computes V^T directly so Vt is stored
// (nh*128+c, 1024 l) row-major — the layout the PV B-fragment wants.
// ---------------------------------------------------------------------------
__global__ __launch_bounds__(256, 2) void mlp_v_kernel(
    const float* __restrict__ X, const float* __restrict__ W1,
    const float* __restrict__ b1, const float* __restrict__ W2,
    const float* __restrict__ b2, f16_t* __restrict__ Vt) {
  __shared__ __align__(16) f16_t sX[64 * 72];     // X then H (rows=l)
  __shared__ __align__(16) f16_t sW[128 * 72];    // W^T half; then V^T tile
  __shared__ float sB[128];

  const int tid  = threadIdx.x;
  const int lane = tid & 63;
  const int wave = tid >> 6;
  const int q    = lane >> 4;
  const int c15  = lane & 15;
  const size_t rowBase = (size_t)blockIdx.x * 64;
  const floatx4 FZ = {0.f, 0.f, 0.f, 0.f};

  floatx4 acc1[8];
  for (int i = 0; i < 8; ++i) acc1[i] = FZ;

  for (int kh = 0; kh < 2; ++kh) {
    __syncthreads();
    for (int u = 0; u < 4; ++u) {
      int idx = tid + u * 256;
      int r = idx >> 4;
      int c4 = (idx & 15) << 2;
      float4 v = *(const float4*)(X + rowBase * 128 + (size_t)r * 128 + kh * 64 + c4);
      int o = r * 72 + c4;
      sX[o + 0] = (f16_t)v.x; sX[o + 1] = (f16_t)v.y;
      sX[o + 2] = (f16_t)v.z; sX[o + 3] = (f16_t)v.w;
    }
    for (int u = 0; u < 8; ++u) {
      int idx = tid + u * 256;
      int k = idx >> 5;
      int n4 = (idx & 31) << 2;
      float4 v = *(const float4*)(W1 + (size_t)(kh * 64 + k) * 128 + n4);
      sW[(n4 + 0) * 72 + k] = (f16_t)v.x;
      sW[(n4 + 1) * 72 + k] = (f16_t)v.y;
      sW[(n4 + 2) * 72 + k] = (f16_t)v.z;
      sW[(n4 + 3) * 72 + k] = (f16_t)v.w;
    }
    if (kh == 0 && tid < 128) sB[tid] = b1[tid];
    __syncthreads();

    f16x8 a[2];
    for (int kc = 0; kc < 2; ++kc)
      a[kc] = *(const f16x8*)(sX + (wave * 16 + c15) * 72 + kc * 32 + q * 8);
    for (int nt = 0; nt < 8; ++nt)
      for (int kc = 0; kc < 2; ++kc) {
        f16x8 b = *(const f16x8*)(sW + (nt * 16 + c15) * 72 + kc * 32 + q * 8);
        acc1[nt] = mfma_f16(a[kc], b, acc1[nt]);
      }
  }
  float hreg[8][4];
  for (int nt = 0; nt < 8; ++nt)
    for (int r = 0; r < 4; ++r)
      hreg[nt][r] = fmaxf(acc1[nt][r] + sB[nt * 16 + c15], 0.f);

  // stage 2: D[c_out][l] = sum_k W2t[c_out][k] * H[l][k]
  floatx4 acc2[2][4];
  for (int i = 0; i < 2; ++i) for (int j = 0; j < 4; ++j) acc2[i][j] = FZ;
  for (int kh = 0; kh < 2; ++kh) {
    __syncthreads();
    for (int nt = 4 * kh; nt < 4 * kh + 4; ++nt)
      for (int r = 0; r < 4; ++r) {
        int row = wave * 16 + q * 4 + r;
        sX[row * 72 + (nt - 4 * kh) * 16 + c15] = (f16_t)hreg[nt][r];
      }
    for (int u = 0; u < 8; ++u) {
      int idx = tid + u * 256;
      int k = idx >> 5;
      int n4 = (idx & 31) << 2;
      float4 v = *(const float4*)(W2 + (size_t)(kh * 64 + k) * 128 + n4);
      sW[(n4 + 0) * 72 + k] = (f16_t)v.x;
      sW[(n4 + 1) * 72 + k] = (f16_t)v.y;
      sW[(n4 + 2) * 72 + k] = (f16_t)v.z;
      sW[(n4 + 3) * 72 + k] = (f16_t)v.w;
    }
    if (kh == 0 && tid < 128) sB[tid] = b2[tid];
    __syncthreads();

    f16x8 aw[2][2];
    for (int mt = 0; mt < 2; ++mt)
      for (int kc = 0; kc < 2; ++kc)
        aw[mt][kc] = *(const f16x8*)(sW + ((wave * 2 + mt) * 16 + c15) * 72 + kc * 32 + q * 8);
    for (int nt = 0; nt < 4; ++nt)
      for (int kc = 0; kc < 2; ++kc) {
        f16x8 bh = *(const f16x8*)(sX + (nt * 16 + c15) * 72 + kc * 32 + q * 8);
        for (int mt = 0; mt < 2; ++mt)
          acc2[mt][nt] = mfma_f16(aw[mt][kc], bh, acc2[mt][nt]);
      }
  }
  // write V^T tile (c=128 rows, l=64 cols) into sW, then coalesced copy-out
  __syncthreads();
  for (int mt = 0; mt < 2; ++mt)
    for (int nt = 0; nt < 4; ++nt)
      for (int r = 0; r < 4; ++r) {
        int cr = (wave * 2 + mt) * 16 + q * 4 + r;
        float vv = acc2[mt][nt][r] + sB[cr];
        sW[cr * 72 + nt * 16 + c15] = (f16_t)vv;
      }
  __syncthreads();
  const int nh = (int)(rowBase >> 10);
  const int lB = (int)(rowBase & 1023);
  for (int u = 0; u < 4; ++u) {
    int idx = tid + u * 256;             // 1024 b128 units: 128 c x 8
    int c = idx >> 3;
    int l8 = (idx & 7) << 3;
    *(int4*)(Vt + ((size_t)(nh * 128 + c)) * 1024 + lB + l8) =
        *(const int4*)(sW + c * 72 + l8);
  }
}

// ---------------------------------------------------------------------------
// Kernel 3: fused attention. 128 Q-rows/block, L-tiles of 32.
// S = QK^T (split-bf16, 3 MFMAs), P = mask*exp(-(S^2)/tau), denom scalar,
// O += P@V (fp16 MFMA), final O/denom.
// ---------------------------------------------------------------------------
__global__ __launch_bounds__(256, 2) void attn_kernel(
    const float* __restrict__ Q, const float* __restrict__ t1,
    const float* __restrict__ X, const float* __restrict__ ltau,
    const bf16_t* __restrict__ Khi, const bf16_t* __restrict__ Klo,
    const f16_t* __restrict__ Vt, float* __restrict__ out) {
  __shared__ __align__(16) bf16_t sK[2 * 32 * 136];  // [hi | lo], 272B/row (16B pad)
  __shared__ __align__(16) f16_t sV[128 * 40];       // V^T tile, 80B/row (16B pad)
  __shared__ __align__(16) f16_t sP[128 * 40];
  __shared__ float sT1[128];
  __shared__ float sT2[32];

  const int tid  = threadIdx.x;
  const int lane = tid & 63;
  const int wave = tid >> 6;
  const int q    = lane >> 4;
  const int c15  = lane & 15;
  const int nh   = blockIdx.x >> 3;
  const int tBase = (blockIdx.x & 7) << 7;
  const int n    = nh >> 3;
  const float inv_tau = __expf(-ltau[0]);
  const floatx4 FZ = {0.f, 0.f, 0.f, 0.f};

  if (tid < 128) sT1[tid] = t1[(n << 10) + tBase + tid];

  // Q fragments in registers, hi/lo split: wave owns rows [tBase+wave*32, +32)
  bf16x8 qh[2][4], ql[2][4];
  for (int mt = 0; mt < 2; ++mt) {
    int t = tBase + (wave * 2 + mt) * 16 + c15;
    const float* qr = Q + ((size_t)(nh << 10) + t) * 128;
    for (int kc = 0; kc < 4; ++kc) {
      const float* p = qr + kc * 32 + q * 8;
      float4 v0 = *(const float4*)p;
      float4 v1 = *(const float4*)(p + 4);
      float vv[8] = {v0.x, v0.y, v0.z, v0.w, v1.x, v1.y, v1.z, v1.w};
      bf16x8 h, l;
      for (int j = 0; j < 8; ++j) {
        bf16_t hj = (bf16_t)vv[j];
        h[j] = hj;
        l[j] = (bf16_t)(vv[j] - (float)hj);
      }
      qh[mt][kc] = h;
      ql[mt][kc] = l;
    }
  }
  __syncthreads();
  float t1v[2][4];
  for (int mt = 0; mt < 2; ++mt)
    for (int r = 0; r < 4; ++r)
      t1v[mt][r] = sT1[(wave * 2 + mt) * 16 + q * 4 + r];

  floatx4 O[2][8];
  for (int i = 0; i < 2; ++i) for (int j = 0; j < 8; ++j) O[i][j] = FZ;
  float ds[2][4] = {{0.f, 0.f, 0.f, 0.f}, {0.f, 0.f, 0.f, 0.f}};

  for (int it = 0; it < 32; ++it) {
    const int l0 = it << 5;
    __syncthreads();
    // async-stage K hi/lo (17 KB) and V^T (10 KB) tiles; pad slots get dummy data
    for (int j = wave; j < 27; j += 4) {
      if (j < 17) {
        int o = j * 1024 + lane * 16;
        int half = (o >= 8704) ? 1 : 0;
        int rem2 = o - half * 8704;
        int row = rem2 / 272;
        int rem = rem2 - row * 272;
        const bf16_t* src = half ? Klo : Khi;
        const char* g = (const char*)src +
            (((size_t)((nh << 10) + l0 + row)) << 8) + (rem < 256 ? rem : 0);
        async_ld16((char*)sK + o, g);
      } else {
        int o = (j - 17) * 1024 + lane * 16;
        int c = o / 80;
        int rem = o - c * 80;
        const char* g = (const char*)Vt +
            (((size_t)((nh << 7) + c)) << 11) + (l0 << 1) + (rem < 64 ? rem : 0);
        async_ld16((char*)sV + o, g);
      }
    }
    if (tid < 32) sT2[tid] = X[((size_t)(n << 13) + l0 + tid) * 128 + 127];
    __syncthreads();

    float t2v[2];
    t2v[0] = sT2[c15];
    t2v[1] = sT2[16 + c15];

    floatx4 S[2][2];
    S[0][0] = FZ; S[0][1] = FZ; S[1][0] = FZ; S[1][1] = FZ;
    for (int nt = 0; nt < 2; ++nt)
      for (int kc = 0; kc < 4; ++kc) {
        int bo = (nt * 16 + c15) * 136 + kc * 32 + q * 8;
        bf16x8 bh = *(const bf16x8*)(sK + bo);
        bf16x8 bl = *(const bf16x8*)(sK + 4352 + bo);
        for (int mt = 0; mt < 2; ++mt) {
          S[mt][nt] = mfma_bf16(qh[mt][kc], bh, S[mt][nt]);
          S[mt][nt] = mfma_bf16(qh[mt][kc], bl, S[mt][nt]);
          S[mt][nt] = mfma_bf16(ql[mt][kc], bh, S[mt][nt]);
        }
      }
    // elementwise: score -> masked exp -> P (LDS, wave-local rows) + denom
    for (int mt = 0; mt < 2; ++mt)
      for (int nt = 0; nt < 2; ++nt)
        for (int r = 0; r < 4; ++r) {
          float s = S[mt][nt][r];
          float e = __expf(-s * s * inv_tau);
          bool msk = (t1v[mt][r] >= t2v[nt]);
          ds[mt][r] += msk ? e : 1.f;
          float p = msk ? e : 0.f;
          int row = (wave * 2 + mt) * 16 + q * 4 + r;
          sP[row * 40 + nt * 16 + c15] = (f16_t)p;
        }
    // O += P@V (k = 32, one chunk)
    f16x8 ap[2];
    for (int mt = 0; mt < 2; ++mt)
      ap[mt] = *(const f16x8*)(sP + ((wave * 2 + mt) * 16 + c15) * 40 + q * 8);
    for (int ct = 0; ct < 8; ++ct) {
      f16x8 bv = *(const f16x8*)(sV + (ct * 16 + c15) * 40 + q * 8);
      for (int mt = 0; mt < 2; ++mt)
        O[mt][ct] = mfma_f16(ap[mt], bv, O[mt][ct]);
    }
  }
  // reduce per-row denominators across the 16 lanes of each quad-row group
  for (int mt = 0; mt < 2; ++mt)
    for (int r = 0; r < 4; ++r) {
      float v = ds[mt][r];
      v += __shfl_xor(v, 1);
      v += __shfl_xor(v, 2);
      v += __shfl_xor(v, 4);
      v += __shfl_xor(v, 8);
      ds[mt][r] = 1.f / v;
    }
  for (int mt = 0; mt < 2; ++mt) {
    int rowb = tBase + (wave * 2 + mt) * 16 + q * 4;
    for (int ct = 0; ct < 8; ++ct)
      for (int r = 0; r < 4; ++r)
        out[((size_t)(nh << 10) + rowb + r) * 128 + ct * 16 + c15] =
            O[mt][ct][r] * ds[mt][r];
  }
}

extern "C" void kernel_launch(void* const* d_in, const int* in_sizes, int n_in,
                              void* d_out, int out_size, void* d_ws, size_t ws_size,
                              hipStream_t stream) {
  const float* X   = (const float*)d_in[0];
  const float* t1  = (const float*)d_in[1];
  const float* Q   = (const float*)d_in[2];
  const float* Wk1 = (const float*)d_in[3];
  const float* bk1 = (const float*)d_in[4];
  const float* Wk2 = (const float*)d_in[5];
  const float* bk2 = (const float*)d_in[6];
  const float* Wv1 = (const float*)d_in[7];
  const float* bv1 = (const float*)d_in[8];
  const float* Wv2 = (const float*)d_in[9];
  const float* bv2 = (const float*)d_in[10];
  const float* log_tau = (const float*)d_in[11];
  float* out = (float*)d_out;

  const size_t E = (size_t)64 * 1024 * 128;  // 8388608 elements per array
  bf16_t* Khi = (bf16_t*)d_ws;
  bf16_t* Klo = Khi + E;
  f16_t*  Vt  = (f16_t*)(Klo + E);

  mlp_k_kernel<<<1024, 256, 0, stream>>>(X, Wk1, bk1, Wk2, bk2, Khi, Klo);
  mlp_v_kernel<<<1024, 256, 0, stream>>>(X, Wv1, bv1, Wv2, bv2, Vt);
  attn_kernel<<<512, 256, 0, stream>>>(Q, t1, X, log_tau, Khi, Klo, Vt, out);
}

// Round 2
// 242.769 us; speedup vs baseline: 1.3444x; 1.3444x over previous
//
#include <hip/hip_runtime.h>
#include <hip/hip_bf16.h>

typedef __bf16 bf16_t;
typedef _Float16 f16_t;
typedef bf16_t bf16x8 __attribute__((ext_vector_type(8)));
typedef f16_t  f16x8  __attribute__((ext_vector_type(8)));
typedef float  floatx4 __attribute__((ext_vector_type(4)));
typedef bf16x8 bf16x8u __attribute__((aligned(8)));   // 8B-aligned view

#define DEV static __device__ __forceinline__

DEV floatx4 mfma_bf16(bf16x8 a, bf16x8 b, floatx4 c) {
  return __builtin_amdgcn_mfma_f32_16x16x32_bf16(a, b, c, 0, 0, 0);
}
DEV floatx4 mfma_f16(f16x8 a, f16x8 b, floatx4 c) {
  return __builtin_amdgcn_mfma_f32_16x16x32_f16(a, b, c, 0, 0, 0);
}
DEV void async_ld16(void* lds, const void* g) {
  __builtin_amdgcn_global_load_lds(
      (const __attribute__((address_space(1))) unsigned int*)g,
      (__attribute__((address_space(3))) unsigned int*)lds, 16, 0, 0);
}

// ---------------------------------------------------------------------------
// Prep: weight transpose+split (blocks 0..15), t2 gather (blocks 16..47).
// W*p layout: [hi: n*128+k | lo: 16384 + n*128+k] bf16 (rows of 256B).
// ---------------------------------------------------------------------------
__global__ void prep_kernel(const float* __restrict__ Wk1, const float* __restrict__ Wk2,
                            const float* __restrict__ Wv1, const float* __restrict__ Wv2,
                            const float* __restrict__ X,
                            bf16_t* __restrict__ W1p, bf16_t* __restrict__ W2p,
                            f16_t* __restrict__ W1f, f16_t* __restrict__ W2f,
                            float* __restrict__ t2pre) {
  int b = blockIdx.x;
  if (b < 16) {
    int m = b >> 2, p = b & 3;
    const float* src = m == 0 ? Wk1 : m == 1 ? Wk2 : m == 2 ? Wv1 : Wv2;
    for (int u = 0; u < 16; ++u) {
      int idx = p * 4096 + u * 256 + threadIdx.x;   // idx = k*128 + n
      int k = idx >> 7, nn = idx & 127;
      float v = src[idx];
      int o = nn * 128 + k;
      if (m == 0) { bf16_t h = (bf16_t)v; W1p[o] = h; W1p[16384 + o] = (bf16_t)(v - (float)h); }
      else if (m == 1) { bf16_t h = (bf16_t)v; W2p[o] = h; W2p[16384 + o] = (bf16_t)(v - (float)h); }
      else if (m == 2) W1f[o] = (f16_t)v;
      else W2f[o] = (f16_t)v;
    }
  } else {
    int i = (b - 16) * 256 + threadIdx.x;           // n*1024 + l
    t2pre[i] = X[((size_t)(i >> 10) * 8192 + (i & 1023)) * 128 + 127];
  }
}

// ---------------------------------------------------------------------------
// MLP-K: split-bf16, 64 rows/block. Weights async-staged in k-quarters from
// pre-split ws. LDS 54272B -> 3 blocks/CU.
// ---------------------------------------------------------------------------
__global__ __launch_bounds__(256) void mlp_k_kernel(
    const float* __restrict__ X, const float* __restrict__ b1,
    const float* __restrict__ b2, const bf16_t* __restrict__ W1p,
    const bf16_t* __restrict__ W2p, bf16_t* __restrict__ Khi,
    bf16_t* __restrict__ Klo) {
  __shared__ __align__(16) bf16_t sXh[64 * 132];   // 264B rows (bank ok, 8B align)
  __shared__ __align__(16) bf16_t sXl[64 * 132];
  __shared__ __align__(16) bf16_t sW[256 * 40];    // [hi 128 | lo 128] rows of 80B

  const int tid = threadIdx.x, lane = tid & 63, wave = tid >> 6;
  const int q = lane >> 4, c15 = lane & 15;
  const size_t rowBase = (size_t)blockIdx.x * 64;
  const floatx4 FZ = {0.f, 0.f, 0.f, 0.f};

  // staging map: 20 KB-chunks over [256 rows][80B], 64B data/row
  int goff[5];
  for (int a = 0; a < 5; ++a) {
    int o = (wave + 4 * a) * 1024 + lane * 16;
    int row = o / 80, rem = o % 80;
    goff[a] = row * 256 + (rem < 64 ? rem : 0);
  }
  float b1v[8], b2v[8];
  for (int nt = 0; nt < 8; ++nt) { b1v[nt] = b1[nt * 16 + c15]; b2v[nt] = b2[nt * 16 + c15]; }

  // X -> hi/lo bf16 (one pass)
  for (int u = 0; u < 8; ++u) {
    int idx = tid + u * 256;                 // 2048 float4 units: 64r x 32
    int r = idx >> 5, c4 = (idx & 31) << 2;
    float4 v = *(const float4*)(X + (rowBase + r) * 128 + c4);
    int o = r * 132 + c4;
    float vv[4] = {v.x, v.y, v.z, v.w};
    for (int i = 0; i < 4; ++i) {
      bf16_t h = (bf16_t)vv[i];
      sXh[o + i] = h;
      sXl[o + i] = (bf16_t)(vv[i] - (float)h);
    }
  }

  auto issueW = [&](const bf16_t* Wp, int kq) {
    const char* base = (const char*)Wp + kq * 64;
    for (int a = 0; a < 5; ++a)
      async_ld16((char*)sW + (wave + 4 * a) * 1024 + lane * 16, base + goff[a]);
  };
  auto gemm = [&](const bf16_t* Wp, floatx4* acc, bool first) {
    for (int kq = 0; kq < 4; ++kq) {
      if (!first || kq) __syncthreads();     // prior sW reads done
      issueW(Wp, kq);
      __syncthreads();                       // staged data visible
      const int ao = (wave * 16 + c15) * 132 + kq * 32 + q * 8;
      bf16x8 ah = *(const bf16x8u*)(sXh + ao);
      bf16x8 al = *(const bf16x8u*)(sXl + ao);
      for (int nt = 0; nt < 8; ++nt) {
        const int bo = (nt * 16 + c15) * 40 + q * 8;
        bf16x8 bh = *(const bf16x8*)(sW + bo);
        bf16x8 bl = *(const bf16x8*)(sW + 128 * 40 + bo);
        acc[nt] = mfma_bf16(ah, bh, acc[nt]);
        acc[nt] = mfma_bf16(ah, bl, acc[nt]);
        acc[nt] = mfma_bf16(al, bh, acc[nt]);
      }
    }
  };

  floatx4 acc1[8];
  for (int i = 0; i < 8; ++i) acc1[i] = FZ;
  gemm(W1p, acc1, true);

  // H = relu(acc1+b1) -> sX hi/lo (wave-local rows, no barrier needed)
  for (int nt = 0; nt < 8; ++nt)
    for (int r = 0; r < 4; ++r) {
      float h = fmaxf(acc1[nt][r] + b1v[nt], 0.f);
      bf16_t hh = (bf16_t)h;
      int o = (wave * 16 + q * 4 + r) * 132 + nt * 16 + c15;
      sXh[o] = hh;
      sXl[o] = (bf16_t)(h - (float)hh);
    }

  floatx4 acc2[8];
  for (int i = 0; i < 8; ++i) acc2[i] = FZ;
  gemm(W2p, acc2, false);

  // epilogue: K hi/lo -> sX (own rows) -> coalesced b128 copy-out
  for (int nt = 0; nt < 8; ++nt)
    for (int r = 0; r < 4; ++r) {
      float kv = acc2[nt][r] + b2v[nt];
      bf16_t kh = (bf16_t)kv;
      int o = (wave * 16 + q * 4 + r) * 132 + nt * 16 + c15;
      sXh[o] = kh;
      sXl[o] = (bf16_t)(kv - (float)kh);
    }
  __syncthreads();
  for (int u = 0; u < 4; ++u) {
    int idx = tid + u * 256;                 // 1024 8-elem chunks
    int r = idx >> 4, c8 = (idx & 15) << 3;
    bf16x8 vh = *(const bf16x8u*)(sXh + r * 132 + c8);
    bf16x8 vl = *(const bf16x8u*)(sXl + r * 132 + c8);
    *(bf16x8*)(Khi + (rowBase + r) * 128 + c8) = vh;
    *(bf16x8*)(Klo + (rowBase + r) * 128 + c8) = vl;
  }
}

// ---------------------------------------------------------------------------
// MLP-V: f16, 64 rows/block; stage 2 emits V^T tile (Vt[c][l]).
// ---------------------------------------------------------------------------
__global__ __launch_bounds__(256) void mlp_v_kernel(
    const float* __restrict__ X, const float* __restrict__ b1,
    const float* __restrict__ b2, const f16_t* __restrict__ W1f,
    const f16_t* __restrict__ W2f, f16_t* __restrict__ Vt) {
  __shared__ __align__(16) f16_t sXf[9216];        // X/H [64][136]; later V^T [128][72]
  __shared__ __align__(16) f16_t sW[128 * 40];     // 10240B

  const int tid = threadIdx.x, lane = tid & 63, wave = tid >> 6;
  const int q = lane >> 4, c15 = lane & 15;
  const size_t rowBase = (size_t)blockIdx.x * 64;
  const floatx4 FZ = {0.f, 0.f, 0.f, 0.f};

  int goff[3];
  for (int a = 0; a < 3; ++a) {
    int j = wave + 4 * a;
    int o = j * 1024 + lane * 16;
    int row = o / 80, rem = o % 80;
    goff[a] = row * 256 + (rem < 64 ? rem : 0);
  }
  float b1v[8], bvv[2][4];
  for (int nt = 0; nt < 8; ++nt) b1v[nt] = b1[nt * 16 + c15];
  for (int mt = 0; mt < 2; ++mt)
    for (int r = 0; r < 4; ++r)
      bvv[mt][r] = b2[(wave * 2 + mt) * 16 + q * 4 + r];

  for (int u = 0; u < 8; ++u) {
    int idx = tid + u * 256;
    int r = idx >> 5, c4 = (idx & 31) << 2;
    float4 v = *(const float4*)(X + (rowBase + r) * 128 + c4);
    int o = r * 136 + c4;
    sXf[o + 0] = (f16_t)v.x; sXf[o + 1] = (f16_t)v.y;
    sXf[o + 2] = (f16_t)v.z; sXf[o + 3] = (f16_t)v.w;
  }

  auto issueV = [&](const f16_t* Wp, int kq) {
    const char* base = (const char*)Wp + kq * 64;
    for (int a = 0; a < 3; ++a) {
      int j = wave + 4 * a;
      if (j < 10) async_ld16((char*)sW + j * 1024 + lane * 16, base + goff[a]);
    }
  };

  floatx4 acc1[8];
  for (int i = 0; i < 8; ++i) acc1[i] = FZ;
  for (int kq = 0; kq < 4; ++kq) {
    if (kq) __syncthreads();
    issueV(W1f, kq);
    __syncthreads();
    f16x8 a = *(const f16x8*)(sXf + (wave * 16 + c15) * 136 + kq * 32 + q * 8);
    for (int nt = 0; nt < 8; ++nt) {
      f16x8 bb = *(const f16x8*)(sW + (nt * 16 + c15) * 40 + q * 8);
      acc1[nt] = mfma_f16(a, bb, acc1[nt]);
    }
  }
  // H -> sXf (own rows)
  for (int nt = 0; nt < 8; ++nt)
    for (int r = 0; r < 4; ++r)
      sXf[(wave * 16 + q * 4 + r) * 136 + nt * 16 + c15] =
          (f16_t)fmaxf(acc1[nt][r] + b1v[nt], 0.f);

  // stage 2: D[c][l] = sum_k W2t[c][k] H[l][k]  (A = W2t, B = H, cross-wave reads)
  floatx4 acc2[2][4];
  for (int i = 0; i < 2; ++i) for (int j = 0; j < 4; ++j) acc2[i][j] = FZ;
  for (int kq = 0; kq < 4; ++kq) {
    __syncthreads();                         // H visible / sW reuse
    issueV(W2f, kq);
    __syncthreads();
    f16x8 aw0 = *(const f16x8*)(sW + ((wave * 2 + 0) * 16 + c15) * 40 + q * 8);
    f16x8 aw1 = *(const f16x8*)(sW + ((wave * 2 + 1) * 16 + c15) * 40 + q * 8);
    for (int nt = 0; nt < 4; ++nt) {
      f16x8 bh = *(const f16x8*)(sXf + (nt * 16 + c15) * 136 + kq * 32 + q * 8);
      acc2[0][nt] = mfma_f16(aw0, bh, acc2[0][nt]);
      acc2[1][nt] = mfma_f16(aw1, bh, acc2[1][nt]);
    }
  }
  __syncthreads();                           // all H reads done; reuse sXf as V^T
  for (int mt = 0; mt < 2; ++mt)
    for (int nt = 0; nt < 4; ++nt)
      for (int r = 0; r < 4; ++r) {
        int c = (wave * 2 + mt) * 16 + q * 4 + r;
        sXf[c * 72 + nt * 16 + c15] = (f16_t)(acc2[mt][nt][r] + bvv[mt][r]);
      }
  __syncthreads();
  const int nh = (int)(rowBase >> 10);
  const int lB = (int)(rowBase & 1023);
  for (int u = 0; u < 4; ++u) {
    int idx = tid + u * 256;                 // 1024 8-f16 chunks
    int c = idx >> 3, l8 = (idx & 7) << 3;
    *(f16x8*)(Vt + ((size_t)nh * 128 + c) * 1024 + lB + l8) =
        *(const f16x8*)(sXf + c * 72 + l8);
  }
}

// ---------------------------------------------------------------------------
// attn: 128 Q-rows/block, 32-L tiles, double-buffered cross-iter prefetch,
// 1 barrier/iter, XCD-aware head swizzle.
// ---------------------------------------------------------------------------
__global__ __launch_bounds__(256) void attn_kernel(
    const float* __restrict__ Q, const float* __restrict__ t1,
    const float* __restrict__ t2pre, const float* __restrict__ ltau,
    const bf16_t* __restrict__ Khi, const bf16_t* __restrict__ Klo,
    const f16_t* __restrict__ Vt, float* __restrict__ out) {
  __shared__ __align__(16) char sBuf[2][27648];    // [K hi/lo 17408 | V 10240]
  __shared__ __align__(16) f16_t sP[128 * 40];

  const int tid = threadIdx.x, lane = tid & 63, wave = tid >> 6;
  const int q = lane >> 4, c15 = lane & 15;
  const int nh = blockIdx.x & 63;                  // same head -> same XCD (blk%8 const)
  const int tB = (blockIdx.x >> 6) << 7;
  const int n = nh >> 3;
  const float c2 = __expf(-ltau[0]) * 1.44269504f; // exp(-s^2/tau) = exp2(-s^2*c2)
  const floatx4 FZ = {0.f, 0.f, 0.f, 0.f};

  // precomputed staging slots (27 KB-chunks: K 17 + V 10)
  const char* gp[7]; int ls[7]; int st[7];
  for (int a = 0; a < 7; ++a) {
    int j = wave + 4 * a;
    gp[a] = nullptr; ls[a] = 0; st[a] = 0;
    if (j < 17) {
      int o = j * 1024 + lane * 16;
      int half = o >= 8704 ? 1 : 0;
      int r2 = o - half * 8704;
      int row = r2 / 272, rem = r2 % 272;
      if (rem >= 256) rem = 0;
      gp[a] = (const char*)(half ? Klo : Khi) + ((size_t)((nh << 10) + row)) * 256 + rem;
      st[a] = 8192; ls[a] = o;
    } else if (j < 27) {
      int o = (j - 17) * 1024 + lane * 16;
      int c = o / 80, rem = o % 80;
      if (rem >= 64) rem = 0;
      gp[a] = (const char*)Vt + ((size_t)((nh << 7) + c)) * 2048 + rem;
      st[a] = 64; ls[a] = 17408 + o;
    }
  }
  auto stage = [&](int buf) {
    for (int a = 0; a < 7; ++a) {
      int j = wave + 4 * a;
      if (j < 27) { async_ld16(sBuf[buf] + ls[a], gp[a]); gp[a] += st[a]; }
    }
  };

  // Q fragments hi/lo in registers
  bf16x8 qh[2][4], ql[2][4];
  for (int mt = 0; mt < 2; ++mt) {
    int t = tB + (wave * 2 + mt) * 16 + c15;
    const float* qr = Q + ((size_t)(nh << 10) + t) * 128;
    for (int kc = 0; kc < 4; ++kc) {
      const float* p = qr + kc * 32 + q * 8;
      float4 v0 = *(const float4*)p;
      float4 v1 = *(const float4*)(p + 4);
      float vv[8] = {v0.x, v0.y, v0.z, v0.w, v1.x, v1.y, v1.z, v1.w};
      bf16x8 h, l;
      for (int j = 0; j < 8; ++j) {
        bf16_t hj = (bf16_t)vv[j];
        h[j] = hj;
        l[j] = (bf16_t)(vv[j] - (float)hj);
      }
      qh[mt][kc] = h;
      ql[mt][kc] = l;
    }
  }
  float t1v[2][4];
  for (int mt = 0; mt < 2; ++mt)
    for (int r = 0; r < 4; ++r)
      t1v[mt][r] = t1[(n << 10) + tB + (wave * 2 + mt) * 16 + q * 4 + r];
  const float* t2p = t2pre + (n << 10);

  floatx4 O[2][8];
  for (int i = 0; i < 2; ++i) for (int j = 0; j < 8; ++j) O[i][j] = FZ;
  float ds[2][4] = {{0.f, 0.f, 0.f, 0.f}, {0.f, 0.f, 0.f, 0.f}};

  stage(0);
  __syncthreads();
  for (int it = 0; it < 32; ++it) {
    const int cur = it & 1;
    if (it < 31) stage(cur ^ 1);             // prefetch next tile; drained at iter-end barrier
    float t2a = t2p[c15], t2b = t2p[c15 + 16];
    t2p += 32;
    const bf16_t* kb = (const bf16_t*)sBuf[cur];
    const f16_t* vb = (const f16_t*)(sBuf[cur] + 17408);

    floatx4 S[2][2];
    S[0][0] = FZ; S[0][1] = FZ; S[1][0] = FZ; S[1][1] = FZ;
    for (int nt = 0; nt < 2; ++nt)
      for (int kc = 0; kc < 4; ++kc) {
        int bo = (nt * 16 + c15) * 136 + kc * 32 + q * 8;
        bf16x8 bh = *(const bf16x8*)(kb + bo);
        bf16x8 bl = *(const bf16x8*)(kb + 4352 + bo);
        for (int mt = 0; mt < 2; ++mt) {
          S[mt][nt] = mfma_bf16(qh[mt][kc], bh, S[mt][nt]);
          S[mt][nt] = mfma_bf16(qh[mt][kc], bl, S[mt][nt]);
          S[mt][nt] = mfma_bf16(ql[mt][kc], bh, S[mt][nt]);
        }
      }
    for (int mt = 0; mt < 2; ++mt)
      for (int nt = 0; nt < 2; ++nt) {
        float t2v = nt ? t2b : t2a;
        for (int r = 0; r < 4; ++r) {
          float s = S[mt][nt][r];
          float e = exp2f(-s * s * c2);
          bool m = (t1v[mt][r] >= t2v);
          ds[mt][r] += m ? e : 1.f;
          sP[((wave * 2 + mt) * 16 + q * 4 + r) * 40 + nt * 16 + c15] =
              (f16_t)(m ? e : 0.f);
        }
      }
    f16x8 ap[2];
    for (int mt = 0; mt < 2; ++mt)
      ap[mt] = *(const f16x8*)(sP + ((wave * 2 + mt) * 16 + c15) * 40 + q * 8);
    for (int ct = 0; ct < 8; ++ct) {
      f16x8 bv = *(const f16x8*)(vb + (ct * 16 + c15) * 40 + q * 8);
      for (int mt = 0; mt < 2; ++mt)
        O[mt][ct] = mfma_f16(ap[mt], bv, O[mt][ct]);
    }
    __syncthreads();                         // publishes prefetched tile; frees cur for reuse
  }

  for (int mt = 0; mt < 2; ++mt)
    for (int r = 0; r < 4; ++r) {
      float v = ds[mt][r];
      v += __shfl_xor(v, 1);
      v += __shfl_xor(v, 2);
      v += __shfl_xor(v, 4);
      v += __shfl_xor(v, 8);
      ds[mt][r] = 1.f / v;
    }
  for (int mt = 0; mt < 2; ++mt) {
    int rowb = tB + (wave * 2 + mt) * 16 + q * 4;
    for (int ct = 0; ct < 8; ++ct)
      for (int r = 0; r < 4; ++r)
        out[((size_t)(nh << 10) + rowb + r) * 128 + ct * 16 + c15] =
            O[mt][ct][r] * ds[mt][r];
  }
}

extern "C" void kernel_launch(void* const* d_in, const int* in_sizes, int n_in,
                              void* d_out, int out_size, void* d_ws, size_t ws_size,
                              hipStream_t stream) {
  const float* X   = (const float*)d_in[0];
  const float* t1  = (const float*)d_in[1];
  const float* Q   = (const float*)d_in[2];
  const float* Wk1 = (const float*)d_in[3];
  const float* bk1 = (const float*)d_in[4];
  const float* Wk2 = (const float*)d_in[5];
  const float* bk2 = (const float*)d_in[6];
  const float* Wv1 = (const float*)d_in[7];
  const float* bv1 = (const float*)d_in[8];
  const float* Wv2 = (const float*)d_in[9];
  const float* bv2 = (const float*)d_in[10];
  const float* log_tau = (const float*)d_in[11];
  float* out = (float*)d_out;

  const size_t E = (size_t)64 * 1024 * 128;
  bf16_t* Khi = (bf16_t*)d_ws;
  bf16_t* Klo = Khi + E;
  f16_t*  Vt  = (f16_t*)(Klo + E);
  bf16_t* W1p = (bf16_t*)((char*)d_ws + 3 * E * 2);
  bf16_t* W2p = W1p + 32768;
  f16_t*  W1f = (f16_t*)(W2p + 32768);
  f16_t*  W2f = W1f + 16384;
  float*  t2pre = (float*)(W2f + 16384);

  prep_kernel<<<48, 256, 0, stream>>>(Wk1, Wk2, Wv1, Wv2, X, W1p, W2p, W1f, W2f, t2pre);
  mlp_k_kernel<<<1024, 256, 0, stream>>>(X, bk1, bk2, W1p, W2p, Khi, Klo);
  mlp_v_kernel<<<1024, 256, 0, stream>>>(X, bv1, bv2, W1f, W2f, Vt);
  attn_kernel<<<512, 256, 0, stream>>>(Q, t1, t2pre, log_tau, Khi, Klo, Vt, out);
}